// Round 4
// baseline (54549.719 us; speedup 1.0000x reference)
//
#include <hip/hip_runtime.h>

// ---------------------------------------------------------------------------
// FarGAN wave head. R2 redesign:
//   - 3 recurrent blocks (one per GRU layer, 384 thr): h-recurrence closes in
//     LDS only; Whh register-resident as MFMA B-frags; 1 raw barrier/step.
//   - 2 GEMM blocks compute gi_{l+1} = bih + Wih@h_l in 32-step chunks, off
//     the critical path (f16 ring via L3, flags at chunk granularity).
//   - gi prefetched 1 step ahead in the recurrent blocks (latency hidden).
// ---------------------------------------------------------------------------

#define B_    16
#define T_    50
#define SPS_  40
#define S_    8000
#define TS_   200
#define GRUIN_ 194
#define TWO_PI_F 6.2831853071795864769f

#define HRING_ 128           // h ring depth (steps)
#define CHK_   32            // gi chunk (steps)
#define GIC_   3             // gi ring chunks

// workspace byte offsets
#define OFF_CTR    0
#define OFF_DV     4096
#define OFF_V      8192
#define OFF_SIN    16384     // 8000*16 f32
#define OFF_COS    528384
#define OFF_PE     1040384   // 16*50*64 f32
#define OFF_COND   1245184   // 16*200*128 f32
#define OFF_GBASE  2883584   // 200*36*64*4 f16
#define OFF_WF     6569984   // 5*216*512 bf16
#define OFF_HRING  7675904   // 2*128*3072 bf16
#define OFF_GI     9248768   // 2*3*32*2304 u64 (f16 gi)
#define OFF_SAMPLE 12787712  // 16*8000 f32
// end 13,299,712 B (< 14.1 MB known-safe)

typedef short s16x8 __attribute__((ext_vector_type(8)));
typedef float f32x4 __attribute__((ext_vector_type(4)));
typedef unsigned long long u64;

__device__ __forceinline__ short f2bf(float f) {
  unsigned u = __float_as_uint(f);
  return (short)((u + 0x7FFFu + ((u >> 16) & 1u)) >> 16);
}
__device__ __forceinline__ float sigm(float x) {
  return __fdividef(1.f, 1.f + __expf(-x));
}
__device__ __forceinline__ float tanhx(float x) {
  float e = __expf(2.f * x);
  return __fdividef(e - 1.f, e + 1.f);
}
__device__ __forceinline__ s16x8 ld_frag_coh(const short* p) {
  union { u64 u[2]; s16x8 v; } r;
  r.u[0] = __hip_atomic_load((const u64*)p,     __ATOMIC_RELAXED, __HIP_MEMORY_SCOPE_AGENT);
  r.u[1] = __hip_atomic_load((const u64*)p + 1, __ATOMIC_RELAXED, __HIP_MEMORY_SCOPE_AGENT);
  return r.v;
}
#define AL(p)    __hip_atomic_load((p),  __ATOMIC_RELAXED, __HIP_MEMORY_SCOPE_AGENT)
#define AS(p,v)  __hip_atomic_store((p), (v), __ATOMIC_RELAXED, __HIP_MEMORY_SCOPE_AGENT)
#define BAR()    asm volatile("s_waitcnt lgkmcnt(0)\n\ts_barrier" ::: "memory")
#define BARVM()  asm volatile("s_waitcnt vmcnt(0) lgkmcnt(0)\n\ts_barrier" ::: "memory")

// ---------------------------------------------------------------------------
__global__ void k_frame(const float* __restrict__ feats,
                        const float* __restrict__ pembed,
                        const float* __restrict__ w1, const float* __restrict__ b1,
                        const float* __restrict__ w2, const float* __restrict__ b2,
                        char* ws) {
  const int bt = blockIdx.x, tid = threadIdx.x;   // 128 thr
  float* dvp = (float*)(ws + OFF_DV);
  float* vp  = (float*)(ws + OFF_V);
  float* pep = (float*)(ws + OFF_PE);
  float* cnd = (float*)(ws + OFF_COND);
  __shared__ float fin[112];
  __shared__ float h1[256];
  __shared__ int   sidx;
  if (tid == 0) {
    float f0 = feats[bt * 48 + 46], vo = feats[bt * 48 + 47];
    float period = fminf(fmaxf(256.f * exp2f(-(f0 + 2.f)), 32.f), 255.f);
    int idx = (int)rintf(period) - 32;
    float f0hz = 16000.f / fmaxf(period, 1.f);
    float v = fminf(fmaxf(vo, 0.f), 1.f);
    float delta = TWO_PI_F * fmaxf(f0hz, 60.f) * (1.f / 16000.f);
    dvp[bt] = delta * v; vp[bt] = v; sidx = idx;
  }
  __syncthreads();
  if (tid < 48) fin[tid] = feats[bt * 48 + tid];
  if (tid < 64) { float pv = pembed[sidx * 64 + tid]; fin[48 + tid] = pv; pep[bt * 64 + tid] = pv; }
  __syncthreads();
  #pragma unroll
  for (int rr = 0; rr < 2; ++rr) {
    int r = tid + rr * 128;
    const float* wr = w1 + r * 112;
    float acc = b1[r];
    #pragma unroll 4
    for (int k = 0; k < 112; ++k) acc += wr[k] * fin[k];
    h1[r] = 0.5f * acc * (1.f + erff(acc * 0.70710678118654752440f));
  }
  __syncthreads();
  const int b = bt / 50, t = bt - b * 50;
  #pragma unroll
  for (int rr = 0; rr < 4; ++rr) {
    int r = tid + rr * 128;
    const float* wr = w2 + r * 256;
    float acc = b2[r];
    #pragma unroll 4
    for (int k = 0; k < 256; ++k) acc += wr[k] * h1[k];
    int sf = r >> 7, c = r & 127;
    cnd[((b * 200) + (t * 4 + sf)) * 128 + c] = acc;
  }
}

// ---------------------------------------------------------------------------
__global__ void k_phase(char* ws) {
  const int b = blockIdx.x, tid = threadIdx.x;    // 256 thr
  const float* dvp = (const float*)(ws + OFF_DV);
  float* sinA = (float*)(ws + OFF_SIN);
  float* cosA = (float*)(ws + OFF_COS);
  __shared__ float ps[200], dvs[200];
  if (tid == 0) {
    float c = 0.f;
    for (int ts = 0; ts < 200; ++ts) {
      float d = dvp[b * 50 + (ts >> 2)];
      dvs[ts] = d;
      float inc = d * (float)SPS_;
      c = c + inc;
      ps[ts] = fmodf(c - inc, TWO_PI_F);
    }
  }
  __syncthreads();
  for (int i = tid; i < S_; i += 256) {
    int ts = i / 40, k = i - ts * 40;
    float ph = ps[ts] + dvs[ts] * (float)k;
    sinA[(size_t)i * 16 + b] = sinf(ph);
    cosA[(size_t)i * 16 + b] = cosf(ph);
  }
}

// ---------------------------------------------------------------------------
// gbase = bih0 + Wc@cond + Wp@pe, f16, MFMA D-tile layout
__global__ void k_gbase(const float* __restrict__ wih0,
                        const float* __restrict__ bih0, char* ws) {
  const int ts = blockIdx.x, tid = threadIdx.x;   // 200 blocks, 256 thr
  const int t = ts >> 2;
  const float* cnd = (const float*)(ws + OFF_COND);
  const float* pep = (const float*)(ws + OFF_PE);
  _Float16* gbp = (_Float16*)(ws + OFF_GBASE);
  __shared__ float c_s[16][128];
  __shared__ float p_s[16][64];
  for (int i = tid; i < 2048; i += 256) c_s[i >> 7][i & 127] = cnd[((i >> 7) * 200 + ts) * 128 + (i & 127)];
  for (int i = tid; i < 1024; i += 256) p_s[i >> 6][i & 63] = pep[((i >> 6) * 50 + t) * 64 + (i & 63)];
  __syncthreads();
  for (int i = tid; i < 9216; i += 256) {
    int row = i >> 4, b = i & 15;
    const float* wr = wih0 + (size_t)row * GRUIN_;
    float acc = bih0[row];
    #pragma unroll 4
    for (int k = 0; k < 128; ++k) acc += wr[k] * c_s[b][k];
    #pragma unroll 4
    for (int k = 0; k < 64; ++k) acc += wr[128 + k] * p_s[b][k];
    int nt = row >> 4, l15 = row & 15;
    int lane = l15 | ((b >> 2) << 4), j = b & 3;
    gbp[((size_t)(ts * 36 + nt) * 64 + lane) * 4 + j] = (_Float16)acc;
  }
}

// ---------------------------------------------------------------------------
// pack 5 matrices into bf16 B-frags: 0=whh0 1=whh1 2=whh2 3=wih1 4=wih2
__global__ void k_wprep(const float* __restrict__ whh0, const float* __restrict__ whh1,
                        const float* __restrict__ whh2, const float* __restrict__ wih1,
                        const float* __restrict__ wih2, char* ws) {
  const int blk = blockIdx.x;           // 1080 blocks, 64 thr
  const int mat = blk / 216, rem = blk - mat * 216;
  const int nt = rem / 6, kt = rem - nt * 6;
  const int lane = threadIdx.x;
  const float* W = (mat == 0) ? whh0 : (mat == 1) ? whh1 : (mat == 2) ? whh2
                  : (mat == 3) ? wih1 : wih2;
  short* dst = (short*)(ws + OFF_WF) + ((size_t)(mat * 36 + nt) * 6 + kt) * 512 + lane * 8;
  const int row = nt * 16 + (lane & 15);
  const int g = lane >> 4;
  #pragma unroll
  for (int e = 0; e < 8; ++e) {
    int k = kt * 32 + 16 * (e >> 2) + 4 * g + (e & 3);
    dst[e] = f2bf(W[(size_t)row * 192 + k]);
  }
}

// ---------------------------------------------------------------------------
// K4: 5 persistent blocks x 384 thr: 0,1,2 = recurrent layers; 3,4 = gi GEMM.
// ---------------------------------------------------------------------------
__global__ __launch_bounds__(384, 1)
void k_gru(char* ws, const float* __restrict__ wih0,
           const float* __restrict__ bhh0, const float* __restrict__ bhh1,
           const float* __restrict__ bhh2, const float* __restrict__ bih1,
           const float* __restrict__ bih2, const float* __restrict__ outw) {
  const int blk = blockIdx.x;
  const int tid = threadIdx.x;
  const int w = tid >> 6, lane = tid & 63, lg = lane >> 4, l15 = lane & 15;

  int* ctr = (int*)ws;                       // hcnt: +l*32 | gicnt: +64+(m-1)*32
                                             // gprog: +128+l*32 | rprog: +192+(m-1)*32
  const short* wf = (const short*)(ws + OFF_WF);
  short* hring    = (short*)(ws + OFF_HRING);
  u64*   giring   = (u64*)(ws + OFF_GI);     // per (layer,chunkslot,step): 2304 u64
  float* sample   = (float*)(ws + OFF_SAMPLE);

  if (blk < 3) {
    // =========================== recurrent block ===========================
    const int l = blk;
    const float* sinA = (const float*)(ws + OFF_SIN);
    const float* cosA = (const float*)(ws + OFF_COS);
    const u64* gbp64  = (const u64*)(ws + OFF_GBASE);
    const float* bhh = (l == 0) ? bhh0 : (l == 1) ? bhh1 : bhh2;

    __shared__ __align__(16) short hbuf[2][3072];   // 6 kt-tiles x 512 bf16
    __shared__ float plds[2][6][16];

    s16x8 WH[3][2][6];
    float bh[3][2];
    #pragma unroll
    for (int g = 0; g < 3; ++g)
      #pragma unroll
      for (int ut = 0; ut < 2; ++ut) {
        int nt = g * 12 + 2 * w + ut;
        #pragma unroll
        for (int kt = 0; kt < 6; ++kt)
          WH[g][ut][kt] = *(const s16x8*)(wf + ((size_t)l * 216 + nt * 6 + kt) * 512 + lane * 8);
        bh[g][ut] = bhh[g * 192 + 32 * w + 16 * ut + l15];
      }
    float wsn[3][2], wcs[3][2];
    if (l == 0) {
      #pragma unroll
      for (int g = 0; g < 3; ++g)
        #pragma unroll
        for (int ut = 0; ut < 2; ++ut) {
          int row = g * 192 + 32 * w + 16 * ut + l15;
          wsn[g][ut] = wih0[(size_t)row * GRUIN_ + 192];
          wcs[g][ut] = wih0[(size_t)row * GRUIN_ + 193];
        }
    }
    float ow0 = 0.f, ow1 = 0.f;
    if (l == 2) { ow0 = outw[32 * w + l15]; ow1 = outw[32 * w + 16 + l15]; }

    for (int i = tid; i < 768; i += 384) ((u64*)hbuf)[i] = 0;
    __syncthreads();

    f32x4 h0v = {0,0,0,0}, h1v = {0,0,0,0};
    f32x4 gbf[3][2];
    u64 giu_cur[6], giu_nxt[6];
    int cur = 0;
    const int lch = ((l15 >> 2) & 3) << 4;

    for (int t = 0; t < S_; ++t) {
      // ---- waits / flow control ----
      if (l > 0 && (t & 31) == 0) {
        if (tid == 0) AS(ctr + 192 + (l - 1) * 32, t >> 5);
        const int tgt = (t >> 5) + 1;
        while (AL(ctr + 64 + (l - 1) * 32) < tgt) __builtin_amdgcn_s_sleep(2);
        asm volatile("" ::: "memory");
      }
      if (l < 2 && (t & 15) == 0 && t >= 112) {
        const int tgt = t - 96;
        while (AL(ctr + 128 + l * 32) < tgt) __builtin_amdgcn_s_sleep(2);
      }
      // ---- gi fetch (cur from prefetch or fresh at chunk head) ----
      if (l > 0) {
        const u64* gib = giring + (size_t)(l - 1) * (GIC_ * CHK_ * 2304);
        if ((t & 31) == 0) {
          const u64* p = gib + ((size_t)(((t >> 5) % GIC_) * CHK_ + (t & 31))) * 2304;
          #pragma unroll
          for (int g = 0; g < 3; ++g)
            #pragma unroll
            for (int ut = 0; ut < 2; ++ut)
              giu_cur[g * 2 + ut] = AL(p + (g * 12 + 2 * w + ut) * 64 + lane);
        } else {
          #pragma unroll
          for (int q = 0; q < 6; ++q) giu_cur[q] = giu_nxt[q];
        }
        if (((t + 1) & 31) != 0 && t + 1 < S_) {
          const u64* p = gib + ((size_t)((((t + 1) >> 5) % GIC_) * CHK_ + ((t + 1) & 31))) * 2304;
          #pragma unroll
          for (int g = 0; g < 3; ++g)
            #pragma unroll
            for (int ut = 0; ut < 2; ++ut)
              giu_nxt[g * 2 + ut] = AL(p + (g * 12 + 2 * w + ut) * 64 + lane);
        }
      }
      f32x4 s4, c4;
      if (l == 0) {
        if (t % 40 == 0) {
          int ts = t / 40;
          #pragma unroll
          for (int g = 0; g < 3; ++g)
            #pragma unroll
            for (int ut = 0; ut < 2; ++ut) {
              union { u64 u; _Float16 h[4]; } up;
              up.u = gbp64[(size_t)(ts * 36 + g * 12 + 2 * w + ut) * 64 + lane];
              f32x4 v; v[0]=(float)up.h[0]; v[1]=(float)up.h[1]; v[2]=(float)up.h[2]; v[3]=(float)up.h[3];
              gbf[g][ut] = v;
            }
        }
        s4 = *(const f32x4*)(sinA + (size_t)t * 16 + lg * 4);
        c4 = *(const f32x4*)(cosA + (size_t)t * 16 + lg * 4);
      }
      // ---- sample store for t-1 (layer2) ----
      if (l == 2 && t > 0 && tid < 16) {
        const int pb = (t - 1) & 1;
        float sm = plds[pb][0][tid] + plds[pb][1][tid] + plds[pb][2][tid]
                 + plds[pb][3][tid] + plds[pb][4][tid] + plds[pb][5][tid];
        sample[(size_t)tid * S_ + (t - 1)] = sm;
      }
      // ---- h-ring publish of h_{t-1} (layers 0,1) ----
      if (l < 2 && t > 0) {
        const u64* sp = (const u64*)(hbuf[cur]) + tid * 2;
        u64 v0 = sp[0], v1 = sp[1];
        u64* rd = (u64*)(hring + (size_t)(l * HRING_ + ((t - 1) & (HRING_ - 1))) * 3072) + tid * 2;
        AS(rd, v0); AS(rd + 1, v1);
      }
      // ---- LDS -> A-frags ----
      s16x8 hf[6];
      #pragma unroll
      for (int kt = 0; kt < 6; ++kt)
        hf[kt] = *(const s16x8*)(hbuf[cur] + kt * 512 + lane * 8);
      // ---- MFMA ----
      f32x4 acc[3][2];
      #pragma unroll
      for (int g = 0; g < 3; ++g)
        #pragma unroll
        for (int ut = 0; ut < 2; ++ut) { f32x4 a = {bh[g][ut],bh[g][ut],bh[g][ut],bh[g][ut]}; acc[g][ut] = a; }
      #pragma unroll
      for (int kt = 0; kt < 6; ++kt)
        #pragma unroll
        for (int g = 0; g < 3; ++g)
          #pragma unroll
          for (int ut = 0; ut < 2; ++ut)
            acc[g][ut] = __builtin_amdgcn_mfma_f32_16x16x32_bf16(hf[kt], WH[g][ut][kt], acc[g][ut], 0, 0, 0);
      // ---- gates ----
      #pragma unroll
      for (int ut = 0; ut < 2; ++ut) {
        f32x4 gr, gz, gn;
        if (l == 0) {
          gr = gbf[0][ut] + s4 * wsn[0][ut] + c4 * wcs[0][ut];
          gz = gbf[1][ut] + s4 * wsn[1][ut] + c4 * wcs[1][ut];
          gn = gbf[2][ut] + s4 * wsn[2][ut] + c4 * wcs[2][ut];
        } else {
          union { u64 u; _Float16 h[4]; } u0, u1, u2;
          u0.u = giu_cur[0 * 2 + ut]; u1.u = giu_cur[1 * 2 + ut]; u2.u = giu_cur[2 * 2 + ut];
          #pragma unroll
          for (int j = 0; j < 4; ++j) { gr[j]=(float)u0.h[j]; gz[j]=(float)u1.h[j]; gn[j]=(float)u2.h[j]; }
        }
        f32x4& hv = ut ? h1v : h0v;
        #pragma unroll
        for (int j = 0; j < 4; ++j) {
          float r = sigm(gr[j] + acc[0][ut][j]);
          float z = sigm(gz[j] + acc[1][ut][j]);
          float n = tanhx(gn[j] + r * acc[2][ut][j]);
          hv[j] = n + z * (hv[j] - n);
        }
      }
      // ---- write h' -> A-frag LDS (buffer cur^1) ----
      {
        short* wb = hbuf[cur ^ 1] + w * 512;
        #pragma unroll
        for (int ut = 0; ut < 2; ++ut) {
          const f32x4& hv = ut ? h1v : h0v;
          #pragma unroll
          for (int j = 0; j < 4; ++j)
            wb[(((lg * 4 + j) | lch) << 3) + ut * 4 + (l15 & 3)] = f2bf(hv[j]);
        }
      }
      // ---- head partials (layer2) ----
      if (l == 2) {
        #pragma unroll
        for (int j = 0; j < 4; ++j) {
          float p = ow0 * h0v[j] + ow1 * h1v[j];
          p += __shfl_xor(p, 1); p += __shfl_xor(p, 2);
          p += __shfl_xor(p, 4); p += __shfl_xor(p, 8);
          if (l15 == 0) plds[t & 1][w][lg * 4 + j] = p;
        }
      }
      // ---- barrier (lgkm only; vm drains every 16 steps for hcnt) ----
      if (l < 2 && (t & 15) == 15) {
        BARVM();
        if (tid == 0) AS(ctr + l * 32, t);
      } else {
        BAR();
      }
      cur ^= 1;
    }
    // ---- tail ----
    if (l < 2) {
      const u64* sp = (const u64*)(hbuf[cur]) + tid * 2;
      u64 v0 = sp[0], v1 = sp[1];
      u64* rd = (u64*)(hring + (size_t)(l * HRING_ + ((S_ - 1) & (HRING_ - 1))) * 3072) + tid * 2;
      AS(rd, v0); AS(rd + 1, v1);
      asm volatile("s_waitcnt vmcnt(0)" ::: "memory");
      __syncthreads();
      if (tid == 0) AS(ctr + l * 32, S_);
    } else {
      if (tid < 16) {
        const int pb = (S_ - 1) & 1;
        float sm = plds[pb][0][tid] + plds[pb][1][tid] + plds[pb][2][tid]
                 + plds[pb][3][tid] + plds[pb][4][tid] + plds[pb][5][tid];
        sample[(size_t)tid * S_ + (S_ - 1)] = sm;
      }
    }
  } else {
    // ============================= GEMM block ==============================
    const int m = blk - 2;          // target layer 1 or 2
    const int lsrc = m - 1;         // source h ring
    const float* bih = (m == 1) ? bih1 : bih2;

    s16x8 WB[6][6];
    float bi[6];
    #pragma unroll
    for (int n6 = 0; n6 < 6; ++n6) {
      const int nt = 6 * w + n6;
      #pragma unroll
      for (int kt = 0; kt < 6; ++kt)
        WB[n6][kt] = *(const s16x8*)(wf + ((size_t)(2 + m) * 216 + nt * 6 + kt) * 512 + lane * 8);
      bi[n6] = bih[nt * 16 + l15];
    }

    for (int c = 0; c < S_ / CHK_; ++c) {
      const int tgt = CHK_ * (c + 1);
      while (AL(ctr + lsrc * 32) < tgt) __builtin_amdgcn_s_sleep(4);
      while (AL(ctr + 192 + (m - 1) * 32) < c - 2) __builtin_amdgcn_s_sleep(4);
      asm volatile("" ::: "memory");

      s16x8 afA[6], afB[6];
      {
        const short* asrc = hring + (size_t)(lsrc * HRING_ + ((CHK_ * c) & (HRING_ - 1))) * 3072 + lane * 8;
        #pragma unroll
        for (int kt = 0; kt < 6; ++kt) afA[kt] = ld_frag_coh(asrc + kt * 512);
      }
      for (int s = 0; s < CHK_; ++s) {
        const int t = CHK_ * c + s;
        if (s + 1 < CHK_) {
          const short* asrc = hring + (size_t)(lsrc * HRING_ + ((t + 1) & (HRING_ - 1))) * 3072 + lane * 8;
          #pragma unroll
          for (int kt = 0; kt < 6; ++kt) afB[kt] = ld_frag_coh(asrc + kt * 512);
        }
        u64* dst = giring + (size_t)(m - 1) * (GIC_ * CHK_ * 2304)
                 + (size_t)((c % GIC_) * CHK_ + s) * 2304 + lane;
        #pragma unroll
        for (int n6 = 0; n6 < 6; ++n6) {
          f32x4 a = {bi[n6], bi[n6], bi[n6], bi[n6]};
          #pragma unroll
          for (int kt = 0; kt < 6; ++kt)
            a = __builtin_amdgcn_mfma_f32_16x16x32_bf16(afA[kt], WB[n6][kt], a, 0, 0, 0);
          union { _Float16 h[4]; u64 u; } pk;
          #pragma unroll
          for (int j = 0; j < 4; ++j) pk.h[j] = (_Float16)a[j];
          AS(dst + (6 * w + n6) * 64, pk.u);
        }
        #pragma unroll
        for (int kt = 0; kt < 6; ++kt) afA[kt] = afB[kt];
      }
      asm volatile("s_waitcnt vmcnt(0)" ::: "memory");
      __syncthreads();
      if (tid == 0) {
        AS(ctr + 64 + (m - 1) * 32, c + 1);
        AS(ctr + 128 + lsrc * 32, CHK_ * (c + 1));
      }
    }
  }
}

// ---------------------------------------------------------------------------
__global__ void k_final(char* ws, const float* __restrict__ noise,
                        const float* __restrict__ outb, const float* __restrict__ lgain,
                        float* __restrict__ out) {
  int i = blockIdx.x * 256 + threadIdx.x;
  if (i >= B_ * S_) return;
  int b = i / S_, s = i - b * S_;
  const float* sample = (const float*)(ws + OFF_SAMPLE);
  const float* vp     = (const float*)(ws + OFF_V);
  float smp = sample[(size_t)b * S_ + s] + outb[0];
  float v = vp[b * 50 + s / 160];
  float noisy = 0.6f * smp + 0.4f * (noise[(size_t)b * S_ + s] * 0.003f);
  float sm2 = v * smp + (1.f - v) * noisy;
  float wave = fminf(fmaxf(sm2, -1.f), 1.f);
  float gain = fminf(fmaxf(expf(lgain[0]), 0.5f), 1.5f);
  out[i] = 1.1f * tanhf(0.9f * gain * wave);
}

// ---------------------------------------------------------------------------
extern "C" void kernel_launch(void* const* d_in, const int* in_sizes, int n_in,
                              void* d_out, int out_size, void* d_ws, size_t ws_size,
                              hipStream_t stream) {
  (void)in_sizes; (void)n_in; (void)out_size; (void)ws_size;
  const float* feats  = (const float*)d_in[0];
  const float* noise  = (const float*)d_in[1];
  const float* pembed = (const float*)d_in[2];
  const float* fpw1   = (const float*)d_in[3];
  const float* fpb1   = (const float*)d_in[4];
  const float* fpw2   = (const float*)d_in[5];
  const float* fpb2   = (const float*)d_in[6];
  const float* outw   = (const float*)d_in[7];
  const float* outb   = (const float*)d_in[8];
  const float* lgain  = (const float*)d_in[9];
  const float* wih0   = (const float*)d_in[10];
  const float* whh0   = (const float*)d_in[11];
  const float* bih0   = (const float*)d_in[12];
  const float* bhh0   = (const float*)d_in[13];
  const float* wih1   = (const float*)d_in[14];
  const float* whh1   = (const float*)d_in[15];
  const float* bih1   = (const float*)d_in[16];
  const float* bhh1   = (const float*)d_in[17];
  const float* wih2   = (const float*)d_in[18];
  const float* whh2   = (const float*)d_in[19];
  const float* bih2   = (const float*)d_in[20];
  const float* bhh2   = (const float*)d_in[21];
  char* ws = (char*)d_ws;
  float* out = (float*)d_out;

  hipMemsetAsync(ws, 0, 1024, stream);
  hipLaunchKernelGGL(k_wprep, dim3(1080), dim3(64), 0, stream,
                     whh0, whh1, whh2, wih1, wih2, ws);
  hipLaunchKernelGGL(k_frame, dim3(B_ * T_), dim3(128), 0, stream,
                     feats, pembed, fpw1, fpb1, fpw2, fpb2, ws);
  hipLaunchKernelGGL(k_phase, dim3(B_), dim3(256), 0, stream, ws);
  hipLaunchKernelGGL(k_gbase, dim3(TS_), dim3(256), 0, stream, wih0, bih0, ws);
  hipLaunchKernelGGL(k_gru, dim3(5), dim3(384), 0, stream, ws, wih0,
                     bhh0, bhh1, bhh2, bih1, bih2, outw);
  hipLaunchKernelGGL(k_final, dim3((B_ * S_ + 255) / 256), dim3(256), 0, stream,
                     ws, noise, outb, lgain, out);
}

// Round 5
// 35794.934 us; speedup vs baseline: 1.5240x; 1.5240x over previous
//
#include <hip/hip_runtime.h>

// ---------------------------------------------------------------------------
// FarGAN wave head. R4: fix VGPR spill (the real R1-R3 bottleneck).
//   - 3 recurrent blocks (one per layer) x 768 thr = 12 waves; each wave owns
//     16 units -> 18 weight frags = 72 VGPR (fits, no scratch).
//   - 2 GEMM blocks compute gi_{l+1} = bih + Wih@h_l in 32-step chunks.
//   - h'-frag LDS writes XOR-swizzled (bank-conflict fix).
// ---------------------------------------------------------------------------

#define B_    16
#define T_    50
#define SPS_  40
#define S_    8000
#define TS_   200
#define GRUIN_ 194
#define TWO_PI_F 6.2831853071795864769f

#define HRING_ 128           // h ring depth (steps)
#define CHK_   32            // gi chunk (steps)
#define GIC_   3             // gi ring chunks

// workspace byte offsets
#define OFF_CTR    0
#define OFF_DV     4096
#define OFF_V      8192
#define OFF_SIN    16384     // 8000*16 f32
#define OFF_COS    528384
#define OFF_PE     1040384   // 16*50*64 f32
#define OFF_COND   1245184   // 16*200*128 f32
#define OFF_GBASE  2883584   // 200*36*64*4 f16
#define OFF_WF     6569984   // 5*216*512 bf16
#define OFF_HRING  7675904   // 2*128*3072 bf16
#define OFF_GI     9248768   // 2*96*2304 u64 (f16 gi)
#define OFF_SAMPLE 12787712  // 16*8000 f32
// end 13,299,712 B

typedef short s16x8 __attribute__((ext_vector_type(8)));
typedef float f32x4 __attribute__((ext_vector_type(4)));
typedef unsigned long long u64;

__device__ __forceinline__ short f2bf(float f) {
  unsigned u = __float_as_uint(f);
  return (short)((u + 0x7FFFu + ((u >> 16) & 1u)) >> 16);
}
__device__ __forceinline__ float sigm(float x) {
  return __fdividef(1.f, 1.f + __expf(-x));
}
__device__ __forceinline__ float tanhx(float x) {
  float e = __expf(2.f * x);
  return __fdividef(e - 1.f, e + 1.f);
}
__device__ __forceinline__ s16x8 ld_frag_coh(const short* p) {
  union { u64 u[2]; s16x8 v; } r;
  r.u[0] = __hip_atomic_load((const u64*)p,     __ATOMIC_RELAXED, __HIP_MEMORY_SCOPE_AGENT);
  r.u[1] = __hip_atomic_load((const u64*)p + 1, __ATOMIC_RELAXED, __HIP_MEMORY_SCOPE_AGENT);
  return r.v;
}
#define AL(p)    __hip_atomic_load((p),  __ATOMIC_RELAXED, __HIP_MEMORY_SCOPE_AGENT)
#define AS(p,v)  __hip_atomic_store((p), (v), __ATOMIC_RELAXED, __HIP_MEMORY_SCOPE_AGENT)
#define BAR()    asm volatile("s_waitcnt lgkmcnt(0)\n\ts_barrier" ::: "memory")
#define BARVM()  asm volatile("s_waitcnt vmcnt(0) lgkmcnt(0)\n\ts_barrier" ::: "memory")

// ---------------------------------------------------------------------------
__global__ void k_frame(const float* __restrict__ feats,
                        const float* __restrict__ pembed,
                        const float* __restrict__ w1, const float* __restrict__ b1,
                        const float* __restrict__ w2, const float* __restrict__ b2,
                        char* ws) {
  const int bt = blockIdx.x, tid = threadIdx.x;   // 128 thr
  float* dvp = (float*)(ws + OFF_DV);
  float* vp  = (float*)(ws + OFF_V);
  float* pep = (float*)(ws + OFF_PE);
  float* cnd = (float*)(ws + OFF_COND);
  __shared__ float fin[112];
  __shared__ float h1[256];
  __shared__ int   sidx;
  if (tid == 0) {
    float f0 = feats[bt * 48 + 46], vo = feats[bt * 48 + 47];
    float period = fminf(fmaxf(256.f * exp2f(-(f0 + 2.f)), 32.f), 255.f);
    int idx = (int)rintf(period) - 32;
    float f0hz = 16000.f / fmaxf(period, 1.f);
    float v = fminf(fmaxf(vo, 0.f), 1.f);
    float delta = TWO_PI_F * fmaxf(f0hz, 60.f) * (1.f / 16000.f);
    dvp[bt] = delta * v; vp[bt] = v; sidx = idx;
  }
  __syncthreads();
  if (tid < 48) fin[tid] = feats[bt * 48 + tid];
  if (tid < 64) { float pv = pembed[sidx * 64 + tid]; fin[48 + tid] = pv; pep[bt * 64 + tid] = pv; }
  __syncthreads();
  #pragma unroll
  for (int rr = 0; rr < 2; ++rr) {
    int r = tid + rr * 128;
    const float* wr = w1 + r * 112;
    float acc = b1[r];
    #pragma unroll 4
    for (int k = 0; k < 112; ++k) acc += wr[k] * fin[k];
    h1[r] = 0.5f * acc * (1.f + erff(acc * 0.70710678118654752440f));
  }
  __syncthreads();
  const int b = bt / 50, t = bt - b * 50;
  #pragma unroll
  for (int rr = 0; rr < 4; ++rr) {
    int r = tid + rr * 128;
    const float* wr = w2 + r * 256;
    float acc = b2[r];
    #pragma unroll 4
    for (int k = 0; k < 256; ++k) acc += wr[k] * h1[k];
    int sf = r >> 7, c = r & 127;
    cnd[((b * 200) + (t * 4 + sf)) * 128 + c] = acc;
  }
}

// ---------------------------------------------------------------------------
__global__ void k_phase(char* ws) {
  const int b = blockIdx.x, tid = threadIdx.x;    // 256 thr
  const float* dvp = (const float*)(ws + OFF_DV);
  float* sinA = (float*)(ws + OFF_SIN);
  float* cosA = (float*)(ws + OFF_COS);
  __shared__ float ps[200], dvs[200];
  if (tid == 0) {
    float c = 0.f;
    for (int ts = 0; ts < 200; ++ts) {
      float d = dvp[b * 50 + (ts >> 2)];
      dvs[ts] = d;
      float inc = d * (float)SPS_;
      c = c + inc;
      ps[ts] = fmodf(c - inc, TWO_PI_F);
    }
  }
  __syncthreads();
  for (int i = tid; i < S_; i += 256) {
    int ts = i / 40, k = i - ts * 40;
    float ph = ps[ts] + dvs[ts] * (float)k;
    sinA[(size_t)i * 16 + b] = sinf(ph);
    cosA[(size_t)i * 16 + b] = cosf(ph);
  }
}

// ---------------------------------------------------------------------------
// gbase = bih0 + Wc@cond + Wp@pe, f16, MFMA D-tile layout
__global__ void k_gbase(const float* __restrict__ wih0,
                        const float* __restrict__ bih0, char* ws) {
  const int ts = blockIdx.x, tid = threadIdx.x;   // 200 blocks, 256 thr
  const int t = ts >> 2;
  const float* cnd = (const float*)(ws + OFF_COND);
  const float* pep = (const float*)(ws + OFF_PE);
  _Float16* gbp = (_Float16*)(ws + OFF_GBASE);
  __shared__ float c_s[16][128];
  __shared__ float p_s[16][64];
  for (int i = tid; i < 2048; i += 256) c_s[i >> 7][i & 127] = cnd[((i >> 7) * 200 + ts) * 128 + (i & 127)];
  for (int i = tid; i < 1024; i += 256) p_s[i >> 6][i & 63] = pep[((i >> 6) * 50 + t) * 64 + (i & 63)];
  __syncthreads();
  for (int i = tid; i < 9216; i += 256) {
    int row = i >> 4, b = i & 15;
    const float* wr = wih0 + (size_t)row * GRUIN_;
    float acc = bih0[row];
    #pragma unroll 4
    for (int k = 0; k < 128; ++k) acc += wr[k] * c_s[b][k];
    #pragma unroll 4
    for (int k = 0; k < 64; ++k) acc += wr[128 + k] * p_s[b][k];
    int nt = row >> 4, l15 = row & 15;
    int lane = l15 | ((b >> 2) << 4), j = b & 3;
    gbp[((size_t)(ts * 36 + nt) * 64 + lane) * 4 + j] = (_Float16)acc;
  }
}

// ---------------------------------------------------------------------------
// pack 5 matrices into bf16 B-frags: 0=whh0 1=whh1 2=whh2 3=wih1 4=wih2
__global__ void k_wprep(const float* __restrict__ whh0, const float* __restrict__ whh1,
                        const float* __restrict__ whh2, const float* __restrict__ wih1,
                        const float* __restrict__ wih2, char* ws) {
  const int blk = blockIdx.x;           // 1080 blocks, 64 thr
  const int mat = blk / 216, rem = blk - mat * 216;
  const int nt = rem / 6, kt = rem - nt * 6;
  const int lane = threadIdx.x;
  const float* W = (mat == 0) ? whh0 : (mat == 1) ? whh1 : (mat == 2) ? whh2
                  : (mat == 3) ? wih1 : wih2;
  short* dst = (short*)(ws + OFF_WF) + ((size_t)(mat * 36 + nt) * 6 + kt) * 512 + lane * 8;
  const int row = nt * 16 + (lane & 15);
  const int g = lane >> 4;
  #pragma unroll
  for (int e = 0; e < 8; ++e) {
    int k = kt * 32 + 16 * (e >> 2) + 4 * g + (e & 3);
    dst[e] = f2bf(W[(size_t)row * 192 + k]);
  }
}

// ---------------------------------------------------------------------------
// K4: 5 persistent blocks x 768 thr (12 waves).
//   blk 0,1,2 = recurrent layers (wave ut owns units [16ut,16ut+16));
//   blk 3,4   = gi GEMM for layers 1,2.
// ---------------------------------------------------------------------------
__global__ __launch_bounds__(768, 1)
void k_gru(char* ws, const float* __restrict__ wih0,
           const float* __restrict__ bhh0, const float* __restrict__ bhh1,
           const float* __restrict__ bhh2, const float* __restrict__ bih1,
           const float* __restrict__ bih2, const float* __restrict__ outw) {
  const int blk = blockIdx.x;
  const int tid = threadIdx.x;
  const int ut = tid >> 6, lane = tid & 63, lg = lane >> 4, l15 = lane & 15;

  int* ctr = (int*)ws;   // hcnt:+l*32 | gicnt:+64+(m-1)*32 | gprog:+128+l*32 | rprog:+192+(m-1)*32
  const short* wf = (const short*)(ws + OFF_WF);
  short* hring    = (short*)(ws + OFF_HRING);
  u64*   giring   = (u64*)(ws + OFF_GI);
  float* sample   = (float*)(ws + OFF_SAMPLE);

  __shared__ __align__(16) short hbuf[2][3072];
  __shared__ float plds[2][12][16];

  // swizzled 16B-block index for A-frag reads (bank-conflict-free both ways)
  const int rdoff = (lane ^ ((lane >> 4) & 3)) * 8;

  if (blk < 3) {
    // =========================== recurrent block ===========================
    const int l = blk;
    const float* sinA = (const float*)(ws + OFF_SIN);
    const float* cosA = (const float*)(ws + OFF_COS);
    const u64* gbp64  = (const u64*)(ws + OFF_GBASE);
    const float* bhh = (l == 0) ? bhh0 : (l == 1) ? bhh1 : bhh2;

    // weights: 18 frags = 72 VGPR per thread
    s16x8 WH[3][6];
    float bh[3];
    #pragma unroll
    for (int g = 0; g < 3; ++g) {
      const int nt = g * 12 + ut;
      #pragma unroll
      for (int kt = 0; kt < 6; ++kt)
        WH[g][kt] = *(const s16x8*)(wf + ((size_t)l * 216 + nt * 6 + kt) * 512 + lane * 8);
      bh[g] = bhh[g * 192 + 16 * ut + l15];
    }
    float wsn[3], wcs[3];
    if (l == 0) {
      #pragma unroll
      for (int g = 0; g < 3; ++g) {
        int row = g * 192 + 16 * ut + l15;
        wsn[g] = wih0[(size_t)row * GRUIN_ + 192];
        wcs[g] = wih0[(size_t)row * GRUIN_ + 193];
      }
    }
    const float ow = (l == 2) ? outw[16 * ut + l15] : 0.f;

    for (int i = tid; i < 1536; i += 768) ((u64*)hbuf)[i] = 0;
    __syncthreads();

    f32x4 h = {0, 0, 0, 0};
    f32x4 gbf[3];
    u64 gic[3], gin[3];
    int cur = 0;
    // h' write coords (swizzled)
    const int kt_w = ut >> 1;
    const int e_   = ((ut & 1) << 2) | (l15 & 3);
    const int q_   = l15 >> 2;

    for (int t = 0; t < S_; ++t) {
      // ---- flow control ----
      if (l > 0 && (t & 31) == 0) {
        if (tid == 0) AS(ctr + 192 + (l - 1) * 32, t >> 5);
        const int tgt = (t >> 5) + 1;
        while (AL(ctr + 64 + (l - 1) * 32) < tgt) __builtin_amdgcn_s_sleep(2);
        asm volatile("" ::: "memory");
      }
      if (l < 2 && (t & 15) == 0 && t >= 112) {
        const int tgt = t - 96;
        while (AL(ctr + 128 + l * 32) < tgt) __builtin_amdgcn_s_sleep(2);
      }
      // ---- gi resolve + prefetch ----
      if (l > 0) {
        const u64* gib = giring + (size_t)(l - 1) * (GIC_ * CHK_ * 2304);
        if ((t & 31) == 0) {
          const u64* p = gib + (size_t)(((t >> 5) % GIC_) * CHK_ + (t & 31)) * 2304;
          #pragma unroll
          for (int g = 0; g < 3; ++g) gic[g] = AL(p + (12 * g + ut) * 64 + lane);
        } else {
          #pragma unroll
          for (int g = 0; g < 3; ++g) gic[g] = gin[g];
        }
        if (((t + 1) & 31) != 0 && t + 1 < S_) {
          const u64* p = gib + (size_t)((((t + 1) >> 5) % GIC_) * CHK_ + ((t + 1) & 31)) * 2304;
          #pragma unroll
          for (int g = 0; g < 3; ++g) gin[g] = AL(p + (12 * g + ut) * 64 + lane);
        }
      }
      f32x4 s4, c4;
      if (l == 0) {
        if (t % 40 == 0) {
          int ts = t / 40;
          #pragma unroll
          for (int g = 0; g < 3; ++g) {
            union { u64 u; _Float16 hh[4]; } up;
            up.u = gbp64[(size_t)(ts * 36 + 12 * g + ut) * 64 + lane];
            f32x4 v; v[0]=(float)up.hh[0]; v[1]=(float)up.hh[1]; v[2]=(float)up.hh[2]; v[3]=(float)up.hh[3];
            gbf[g] = v;
          }
        }
        s4 = *(const f32x4*)(sinA + (size_t)t * 16 + lg * 4);
        c4 = *(const f32x4*)(cosA + (size_t)t * 16 + lg * 4);
      }
      // ---- sample store for t-1 (layer2) ----
      if (l == 2 && t > 0 && tid < 16) {
        const int pb = (t - 1) & 1;
        float sm = 0.f;
        #pragma unroll
        for (int uu = 0; uu < 12; ++uu) sm += plds[pb][uu][tid];
        sample[(size_t)tid * S_ + (t - 1)] = sm;
      }
      // ---- h-ring publish of h_{t-1} (layers 0,1): 1 u64/thread ----
      if (l < 2 && t > 0) {
        u64 v = ((const u64*)(hbuf[cur]))[tid];
        u64* rd = (u64*)(hring + (size_t)(l * HRING_ + ((t - 1) & (HRING_ - 1))) * 3072) + tid;
        AS(rd, v);
      }
      // ---- LDS -> A-frags (swizzled read) ----
      s16x8 hf[6];
      #pragma unroll
      for (int kt = 0; kt < 6; ++kt)
        hf[kt] = *(const s16x8*)(hbuf[cur] + kt * 512 + rdoff);
      // ---- MFMA: 18 per wave ----
      f32x4 acc[3];
      #pragma unroll
      for (int g = 0; g < 3; ++g) { f32x4 a = {bh[g], bh[g], bh[g], bh[g]}; acc[g] = a; }
      #pragma unroll
      for (int kt = 0; kt < 6; ++kt)
        #pragma unroll
        for (int g = 0; g < 3; ++g)
          acc[g] = __builtin_amdgcn_mfma_f32_16x16x32_bf16(hf[kt], WH[g][kt], acc[g], 0, 0, 0);
      // ---- gates ----
      f32x4 gr, gz, gn;
      if (l == 0) {
        gr = gbf[0] + s4 * wsn[0] + c4 * wcs[0];
        gz = gbf[1] + s4 * wsn[1] + c4 * wcs[1];
        gn = gbf[2] + s4 * wsn[2] + c4 * wcs[2];
      } else {
        union { u64 u; _Float16 hh[4]; } u0, u1, u2;
        u0.u = gic[0]; u1.u = gic[1]; u2.u = gic[2];
        #pragma unroll
        for (int j = 0; j < 4; ++j) { gr[j]=(float)u0.hh[j]; gz[j]=(float)u1.hh[j]; gn[j]=(float)u2.hh[j]; }
      }
      #pragma unroll
      for (int j = 0; j < 4; ++j) {
        float r = sigm(gr[j] + acc[0][j]);
        float z = sigm(gz[j] + acc[1][j]);
        float n = tanhx(gn[j] + r * acc[2][j]);
        h[j] = n + z * (h[j] - n);
      }
      // ---- write h' -> swizzled A-frag LDS ----
      {
        short* wb = hbuf[cur ^ 1] + kt_w * 512;
        #pragma unroll
        for (int j = 0; j < 4; ++j) {
          int b16 = ((4 * lg + j) | (q_ << 4)) ^ q_;
          wb[b16 * 8 + e_] = f2bf(h[j]);
        }
      }
      // ---- head partials (layer2) ----
      if (l == 2) {
        #pragma unroll
        for (int j = 0; j < 4; ++j) {
          float p = ow * h[j];
          p += __shfl_xor(p, 1); p += __shfl_xor(p, 2);
          p += __shfl_xor(p, 4); p += __shfl_xor(p, 8);
          if (l15 == 0) plds[t & 1][ut][lg * 4 + j] = p;
        }
      }
      // ---- barrier ----
      if (l < 2 && (t & 15) == 15) {
        BARVM();
        if (tid == 0) AS(ctr + l * 32, t);
      } else {
        BAR();
      }
      cur ^= 1;
    }
    // ---- tail ----
    if (l < 2) {
      u64 v = ((const u64*)(hbuf[cur]))[tid];
      u64* rd = (u64*)(hring + (size_t)(l * HRING_ + ((S_ - 1) & (HRING_ - 1))) * 3072) + tid;
      AS(rd, v);
      asm volatile("s_waitcnt vmcnt(0)" ::: "memory");
      __syncthreads();
      if (tid == 0) AS(ctr + l * 32, S_);
    } else if (tid < 16) {
      const int pb = (S_ - 1) & 1;
      float sm = 0.f;
      #pragma unroll
      for (int uu = 0; uu < 12; ++uu) sm += plds[pb][uu][tid];
      sample[(size_t)tid * S_ + (S_ - 1)] = sm;
    }
  } else {
    // ============================= GEMM block ==============================
    const int m = blk - 2;          // target layer 1 or 2
    const int lsrc = m - 1;         // source h ring
    const float* bih = (m == 1) ? bih1 : bih2;

    s16x8 WB[3][6];
    float bi[3];
    #pragma unroll
    for (int g = 0; g < 3; ++g) {
      const int nt = 12 * g + ut;
      #pragma unroll
      for (int kt = 0; kt < 6; ++kt)
        WB[g][kt] = *(const s16x8*)(wf + ((size_t)(2 + m) * 216 + nt * 6 + kt) * 512 + lane * 8);
      bi[g] = bih[nt * 16 + l15];
    }

    for (int c = 0; c < S_ / CHK_; ++c) {
      if (tid == 0) {
        const int tgt = CHK_ * (c + 1);
        while (AL(ctr + lsrc * 32) < tgt) __builtin_amdgcn_s_sleep(4);
        while (AL(ctr + 192 + (m - 1) * 32) < c - 2) __builtin_amdgcn_s_sleep(4);
      }
      __syncthreads();

      s16x8 afA[6], afB[6];
      {
        const short* asrc = hring + (size_t)(lsrc * HRING_ + ((CHK_ * c) & (HRING_ - 1))) * 3072;
        #pragma unroll
        for (int kt = 0; kt < 6; ++kt) afA[kt] = ld_frag_coh(asrc + kt * 512 + rdoff);
      }
      for (int s = 0; s < CHK_; ++s) {
        const int t = CHK_ * c + s;
        if (s + 1 < CHK_) {
          const short* asrc = hring + (size_t)(lsrc * HRING_ + ((t + 1) & (HRING_ - 1))) * 3072;
          #pragma unroll
          for (int kt = 0; kt < 6; ++kt) afB[kt] = ld_frag_coh(asrc + kt * 512 + rdoff);
        }
        u64* dst = giring + (size_t)(m - 1) * (GIC_ * CHK_ * 2304)
                 + (size_t)((c % GIC_) * CHK_ + s) * 2304 + lane;
        #pragma unroll
        for (int g = 0; g < 3; ++g) {
          f32x4 a = {bi[g], bi[g], bi[g], bi[g]};
          #pragma unroll
          for (int kt = 0; kt < 6; ++kt)
            a = __builtin_amdgcn_mfma_f32_16x16x32_bf16(afA[kt], WB[g][kt], a, 0, 0, 0);
          union { _Float16 hh[4]; u64 u; } pk;
          #pragma unroll
          for (int j = 0; j < 4; ++j) pk.hh[j] = (_Float16)a[j];
          AS(dst + (12 * g + ut) * 64, pk.u);
        }
        #pragma unroll
        for (int kt = 0; kt < 6; ++kt) afA[kt] = afB[kt];
      }
      asm volatile("s_waitcnt vmcnt(0)" ::: "memory");
      __syncthreads();
      if (tid == 0) {
        AS(ctr + 64 + (m - 1) * 32, c + 1);
        AS(ctr + 128 + lsrc * 32, CHK_ * (c + 1));
      }
    }
  }
}

// ---------------------------------------------------------------------------
__global__ void k_final(char* ws, const float* __restrict__ noise,
                        const float* __restrict__ outb, const float* __restrict__ lgain,
                        float* __restrict__ out) {
  int i = blockIdx.x * 256 + threadIdx.x;
  if (i >= B_ * S_) return;
  int b = i / S_, s = i - b * S_;
  const float* sample = (const float*)(ws + OFF_SAMPLE);
  const float* vp     = (const float*)(ws + OFF_V);
  float smp = sample[(size_t)b * S_ + s] + outb[0];
  float v = vp[b * 50 + s / 160];
  float noisy = 0.6f * smp + 0.4f * (noise[(size_t)b * S_ + s] * 0.003f);
  float sm2 = v * smp + (1.f - v) * noisy;
  float wave = fminf(fmaxf(sm2, -1.f), 1.f);
  float gain = fminf(fmaxf(expf(lgain[0]), 0.5f), 1.5f);
  out[i] = 1.1f * tanhf(0.9f * gain * wave);
}

// ---------------------------------------------------------------------------
extern "C" void kernel_launch(void* const* d_in, const int* in_sizes, int n_in,
                              void* d_out, int out_size, void* d_ws, size_t ws_size,
                              hipStream_t stream) {
  (void)in_sizes; (void)n_in; (void)out_size; (void)ws_size;
  const float* feats  = (const float*)d_in[0];
  const float* noise  = (const float*)d_in[1];
  const float* pembed = (const float*)d_in[2];
  const float* fpw1   = (const float*)d_in[3];
  const float* fpb1   = (const float*)d_in[4];
  const float* fpw2   = (const float*)d_in[5];
  const float* fpb2   = (const float*)d_in[6];
  const float* outw   = (const float*)d_in[7];
  const float* outb   = (const float*)d_in[8];
  const float* lgain  = (const float*)d_in[9];
  const float* wih0   = (const float*)d_in[10];
  const float* whh0   = (const float*)d_in[11];
  const float* bih0   = (const float*)d_in[12];
  const float* bhh0   = (const float*)d_in[13];
  const float* wih1   = (const float*)d_in[14];
  const float* whh1   = (const float*)d_in[15];
  const float* bih1   = (const float*)d_in[16];
  const float* bhh1   = (const float*)d_in[17];
  const float* wih2   = (const float*)d_in[18];
  const float* whh2   = (const float*)d_in[19];
  const float* bih2   = (const float*)d_in[20];
  const float* bhh2   = (const float*)d_in[21];
  char* ws = (char*)d_ws;
  float* out = (float*)d_out;

  hipMemsetAsync(ws, 0, 1024, stream);
  hipLaunchKernelGGL(k_wprep, dim3(1080), dim3(64), 0, stream,
                     whh0, whh1, whh2, wih1, wih2, ws);
  hipLaunchKernelGGL(k_frame, dim3(B_ * T_), dim3(128), 0, stream,
                     feats, pembed, fpw1, fpb1, fpw2, fpb2, ws);
  hipLaunchKernelGGL(k_phase, dim3(B_), dim3(256), 0, stream, ws);
  hipLaunchKernelGGL(k_gbase, dim3(TS_), dim3(256), 0, stream, wih0, bih0, ws);
  hipLaunchKernelGGL(k_gru, dim3(5), dim3(768), 0, stream, ws, wih0,
                     bhh0, bhh1, bhh2, bih1, bih2, outw);
  hipLaunchKernelGGL(k_final, dim3((B_ * S_ + 255) / 256), dim3(256), 0, stream,
                     ws, noise, outb, lgain, out);
}